// Round 14
// baseline (257.129 us; speedup 1.0000x reference)
//
#include <hip/hip_runtime.h>
#include <stdint.h>

#define NSIMS 2048
#define NDIM 8
#define NE (NSIMS * NDIM)      // 16384 elements per timestep
#define NSTEPS 1500
#define TP1 (NSTEPS + 1)       // 1501 trajectory columns
#define TILE 64                // steps per lockstep tile
#define NTILE ((NSTEPS + TILE - 1) / TILE)   // 24 (last tile = 28 steps)
#define NBLK 128               // blocks; 16 sims (128 elements) each
#define EPB 128                // elements per block
#define PROW 130               // ptile row stride in floats (pad 2)
#define SQS 0.031622776601683793f  // float(np.sqrt(0.001))
#define SENT 0x7fffffff

// ---------------- Threefry2x32-20 (exact JAX/Random123) ----------------
__device__ __forceinline__ void tf_block(uint32_t k0, uint32_t k1,
                                         uint32_t x0, uint32_t x1,
                                         uint32_t& o0, uint32_t& o1) {
  const uint32_t k2 = k0 ^ k1 ^ 0x1BD11BDAu;
  x0 += k0; x1 += k1;
#define TF_R(r) { x0 += x1; x1 = (x1 << (r)) | (x1 >> (32 - (r))); x1 ^= x0; }
  TF_R(13) TF_R(15) TF_R(26) TF_R(6)
  x0 += k1; x1 += k2 + 1u;
  TF_R(17) TF_R(29) TF_R(16) TF_R(24)
  x0 += k2; x1 += k0 + 2u;
  TF_R(13) TF_R(15) TF_R(26) TF_R(6)
  x0 += k0; x1 += k1 + 3u;
  TF_R(17) TF_R(29) TF_R(16) TF_R(24)
  x0 += k1; x1 += k2 + 4u;
  TF_R(13) TF_R(15) TF_R(26) TF_R(6)
  x0 += k2; x1 += k0 + 5u;
#undef TF_R
  o0 = x0; o1 = x1;
}

// bits -> uniform(-0.99999994, 1) -> sqrt(2)*erfinv, fast path (validated r10)
__device__ __forceinline__ float bits_to_normal(uint32_t bits) {
#pragma clang fp contract(off)
  const float LO = -0.99999994f;
  float f = __uint_as_float((bits >> 9) | 0x3F800000u) - 1.0f;  // [0,1)
  float u = f * 2.0f + LO;
  u = fmaxf(LO, u);
  float t = __builtin_fmaf(-u, u, 1.0f);   // 1 - u^2, single rounding
  float L = __log2f(t);                    // v_log_f32
  float p;
  if (L > -7.2134752f) {                   // w < 5
    float w = __builtin_fmaf(-0.69314718f, L, -2.5f);
    p = 3.97426059e-08f;
    p = 4.85462660e-07f + p * w;
    p = -4.98282379e-06f + p * w;
    p = -6.21053119e-06f + p * w;
    p = 3.09120051e-04f + p * w;
    p = -1.77303519e-03f + p * w;
    p = -5.90813402e-03f + p * w;
    p = 3.48802730e-01f + p * w;
    p = 2.12331454e+00f + p * w;
  } else {
    float w = sqrtf(-0.69314718f * L) - 3.0f;
    p = -2.83145880e-04f;
    p = 1.42765648e-04f + p * w;
    p = 1.90826058e-03f + p * w;
    p = -5.19501312e-03f + p * w;
    p = 8.11688966e-03f + p * w;
    p = -1.07797881e-02f + p * w;
    p = 1.33485786e-02f + p * w;
    p = 1.41658104e+00f + p * w;
    p = 4.00643424e+00f + p * w;
  }
  return p * u;   // == sqrt(2)*erfinv(u), sqrt(2) pre-folded
}

// ---------------- kernel 0: fold keys for all t ----------------
__global__ void k_fold(uint2* __restrict__ keys) {
  int t = blockIdx.x * blockDim.x + threadIdx.x;
  if (t >= NSTEPS) return;
  uint32_t o0, o1;
  tf_block(0u, 42u, 0u, (uint32_t)t, o0, o1);  // fold_in(key(42), t)
  keys[t] = make_uint2(o0, o1);
}

// ---------------- DPP quad ops ----------------
template <int CTRL>
__device__ __forceinline__ float dppf(float v) {
  int r = __builtin_amdgcn_update_dpp(0, __builtin_bit_cast(int, v), CTRL, 0xF, 0xF, true);
  return __builtin_bit_cast(float, r);
}
template <int CTRL>
__device__ __forceinline__ int dppi(int v) {
  return __builtin_amdgcn_update_dpp(0, v, CTRL, 0xF, 0xF, true);
}
// 0xB1=quad_perm[1,0,3,2](xor1) 0x4E=quad_perm[2,3,0,1](xor2)

// one step, 2 dims/lane, quad = sim. Sum tree ((d0+d1)+(d2+d3))+((d4+d5)+(d6+d7))
// == validated butterfly (commuted operands only -> bit-identical).
// Noise arrives pre-scaled by SQS (same product, computed producer-side).
#define STEP(ST, NZ)                                                    \
  {                                                                     \
    _Pragma("clang fp contract(off)")                                   \
    float h = act0 + act1;                                              \
    float x1 = dppf<0xB1>(h);                                           \
    float t1 = h + x1;                                                  \
    float x2 = dppf<0x4E>(t1);                                          \
    float S = t1 + x2;                                                  \
    const float rec = (S * -0.1f) * 7.0f;                               \
    float a0 = inp0 - 0.1f * pre0;                                      \
    float a1 = inp1 - 0.1f * pre1;                                      \
    float b0 = a0 + rec;                                                \
    float b1 = a1 + rec;                                                \
    pre0 = pre0 + b0 * 0.01f;                                           \
    pre1 = pre1 + b1 * 0.01f;                                           \
    pre0 = pre0 + (NZ).x;                                               \
    pre1 = pre1 + (NZ).y;                                               \
    act0 = fmaxf(pre0, 0.0f);                                           \
    act1 = fmaxf(pre1, 0.0f);                                           \
    float m_ = fmaxf(act0, act1);                                       \
    fc = (m_ >= 1.0f) ? (((ST) < fc) ? (ST) : fc) : fc;                 \
    pt2[(ST) * (PROW / 2) + lane] = make_float2(pre0, pre1);            \
  }

// ---------------- fused producer/consumer megakernel ----------------
// Block = 128 elements (16 sims), 8 waves. Wave 0: recurrence, 2 dims/lane
// (lane l owns elements 2l, 2l+1; quad 4s..4s+3 = sim s). Waves 1..7:
// threefry noise (pre-scaled by SQS) for tile k+1 into LDS ring.
__global__ void __launch_bounds__(512) k_fused(const float* __restrict__ input,
                                               const uint2* __restrict__ keys,
                                               float* __restrict__ out) {
  __shared__ float ring[2][TILE][EPB];  // 64 KB noise double-buffer
  __shared__ float ptile[TILE * PROW];  // 33 KB pre tile (tau x eloc)
  __shared__ float spre[EPB];
  __shared__ float sfroz[EPB];
  __shared__ int sfz;
  const int tid = threadIdx.x;
  const int wid = tid >> 6;          // 0..7
  const int lane = tid & 63;
  const int e0g = (int)blockIdx.x * EPB;
  const size_t actoff = (size_t)NE * TP1;
  float2* const pt2 = (float2*)ptile;          // row stride PROW/2 float2
  float2* const sp2 = (float2*)spre;
  float2* const sf2 = (float2*)sfroz;

  if (tid == 0) sfz = SENT;

  float pre0 = 0.0f, pre1 = 0.0f, act0 = 0.0f, act1 = 0.0f;
  float inp0 = 0.0f, inp1 = 0.0f, s0 = 0.0f, s1 = 0.0f;
  int actv = 1;
  if (wid == 0) {
    float2 iv = ((const float2*)(input + e0g))[lane];
    inp0 = iv.x; inp1 = iv.y;
    const size_t r0 = (size_t)(e0g + 2 * lane) * TP1;   // tau = 0 zeros
    out[r0] = 0.0f;            out[actoff + r0] = 0.0f;
    out[r0 + TP1] = 0.0f;      out[actoff + r0 + TP1] = 0.0f;
  } else {
    // prologue: produce tile 0 (128 rows of 64 lanes; rows = (step, half))
    for (int rr = wid - 1; rr < 2 * TILE; rr += 7) {
      const int st = rr >> 1, half = rr & 1;
      const uint2 fk = keys[st];
      uint32_t o0, o1;
      tf_block(fk.x, fk.y, 0u, (uint32_t)(e0g + half * 64 + lane), o0, o1);
      ring[0][st][half * 64 + lane] = bits_to_normal(o0 ^ o1) * SQS;
    }
  }
  __syncthreads();

  int fz = SENT;
  for (int k = 0; k < NTILE; ++k) {
    const int par = k & 1;
    const int base = k * TILE;
    const int nst = (NSTEPS - base < TILE) ? (NSTEPS - base) : TILE;
    if (wid == 0) {
      // publish frozen state as of END OF PREVIOUS tile (race-free w.r.t.
      // the masked store, which reads only after the next barrier)
      const float fr = actv ? 0.0f : 1.0f;
      sf2[lane] = make_float2(fr, fr);
      sp2[lane] = make_float2(s0, s1);
      int fc = TILE;   // tile-local first-crossing step (lane-local)
      const float2* rg2 = (const float2*)&ring[par][0][0];
#pragma unroll 1
      for (int ch = 0; ch < 2; ++ch) {
        float2 nz[32];
#pragma unroll
        for (int j = 0; j < 32; ++j) nz[j] = rg2[(ch * 32 + j) * (EPB / 2) + lane];
        if (nst == TILE) {
#pragma unroll
          for (int j = 0; j < 32; ++j) STEP(ch * 32 + j, nz[j])
        } else {
#pragma unroll
          for (int j = 0; j < 32; ++j) {
            const int st = ch * 32 + j;
            if (st >= nst) break;
            STEP(st, nz[j])
          }
        }
      }
      // quad-min crossing resolution (off hot path)
      int c = fc;
      { int t_ = dppi<0xB1>(c); c = (t_ < c) ? t_ : c; }
      { int t_ = dppi<0x4E>(c); c = (t_ < c) ? t_ : c; }
      if (actv && c < TILE) {
        const float2 fp = pt2[c * (PROW / 2) + lane];   // pre at crossing step
        for (int s = c + 1; s < TILE; ++s) pt2[s * (PROW / 2) + lane] = fp;
        pre0 = fp.x; pre1 = fp.y;
        act0 = fmaxf(pre0, 0.0f); act1 = fmaxf(pre1, 0.0f);
        s0 = pre0; s1 = pre1;
        actv = 0;
      }
      if (__ballot(actv != 0) == 0ull) {   // all 16 sims frozen
        sp2[lane] = make_float2(s0, s1);   // fresh values for tail fill
        if (lane == 0) sfz = base + nst + 1;
      }
    } else {
      // produce tile k+1
      const int nb = base + TILE;
      for (int rr = wid - 1; rr < 2 * TILE; rr += 7) {
        const int st = rr >> 1, half = rr & 1;
        const int t = nb + st;
        if (t >= NSTEPS) break;
        const uint2 fk = keys[t];
        uint32_t o0, o1;
        tf_block(fk.x, fk.y, 0u, (uint32_t)(e0g + half * 64 + lane), o0, o1);
        ring[par ^ 1][st][half * 64 + lane] = bits_to_normal(o0 ^ o1) * SQS;
      }
    }
    __syncthreads();
    // masked coalesced store: wave w owns elocs w*16..w*16+15, lanes = tau
    {
      float fm[16], sv[16];
#pragma unroll
      for (int i = 0; i < 16; ++i) {
        const int er = wid * 16 + i;
        fm[i] = sfroz[er];
        sv[i] = spre[er];
      }
      if (lane < nst) {
        const int tau = base + 1 + lane;
#pragma unroll
        for (int i = 0; i < 16; ++i) {
          const int er = wid * 16 + i;
          float p = ptile[lane * PROW + er];
          p = (fm[i] > 0.0f) ? sv[i] : p;
          const size_t o = (size_t)(e0g + er) * TP1 + (size_t)tau;
          out[o] = p;
          out[actoff + o] = fmaxf(p, 0.0f);   // act == relu(pre)
        }
      }
    }
    if (sfz != SENT) { fz = sfz; break; }   // uniform exit (read after barrier)
    __syncthreads();                        // protect ptile/ring reuse
  }

  if (fz <= NSTEPS) {
    // post-freeze constant tail, coalesced (lanes over tau)
#pragma unroll
    for (int i = 0; i < 16; ++i) {
      const int er = wid * 16 + i;
      const float p = spre[er];
      const float a = fmaxf(p, 0.0f);
      const size_t ro = (size_t)(e0g + er) * TP1;
      for (int tau = fz + lane; tau <= NSTEPS; tau += 64) {
        out[ro + (size_t)tau] = p;
        out[actoff + ro + (size_t)tau] = a;
      }
    }
  }
}

extern "C" void kernel_launch(void* const* d_in, const int* in_sizes, int n_in,
                              void* d_out, int out_size, void* d_ws, size_t ws_size,
                              hipStream_t stream) {
  const float* input = (const float*)d_in[0];
  float* out = (float*)d_out;
  uint2* keys = (uint2*)d_ws;   // 1500 * 8 B = 12 KB
  if (ws_size < NSTEPS * sizeof(uint2)) return;

  k_fold<<<dim3((NSTEPS + 255) / 256), dim3(256), 0, stream>>>(keys);
  k_fused<<<dim3(NBLK), dim3(512), 0, stream>>>(input, keys, out);
}